// Round 4
// baseline (706.236 us; speedup 1.0000x reference)
//
#include <hip/hip_runtime.h>

#define D 128
#define GROWS 32
#define TCAP 1024   // per-tgt-bucket edge capacity (avg 767, max ~900 @5sigma)
#define SCAP 1024   // per-src-bucket capacity
#define TSPILL 8192
#define SSPILL 8192

// ---------------------------------------------------------------------------
// GCN: out = A_norm @ (x @ W^T) + b.
// R1: per-edge f32 atomics write through HBM (300MB).
// R2: CSR gather; edge atomic pass = 37MB of 32B atomic sectors @650GB/s.
// R3: fusing GEMM didn't hide it (throughput- not latency-bound).
// R4: bucket(64 nodes) two-level build. Phase A: scatter edges to per-bucket
// regions (hot-line cursor atomics only, plain stores). Degree = per-bucket
// LDS histogram (no atomics). Aggregate = per-bucket 64x128 LDS tile with
// ds_add_f32 (no global atomics). Spill paths keep adversarial correctness.
// ---------------------------------------------------------------------------

__global__ __launch_bounds__(256) void k_setup(const float* __restrict__ W,
                                               const int* __restrict__ ei,
                                               float* __restrict__ Wt,
                                               int* __restrict__ flag) {
  int i = blockIdx.x * 256 + threadIdx.x;
  if (i < D * D) {
    int c = i >> 7, k = i & 127;
    Wt[k * D + c] = W[i];  // transpose for coalesced GEMM reads
  }
  if (i == 0) {
    // int64-vs-int32 edge_index layout: ids < 2^31 so int64(LE) odd dwords==0
    flag[0] = (ei[1] == 0 && ei[3] == 0 && ei[5] == 0 && ei[7] == 0) ? 1 : 0;
  }
}

// Phase A: GEMM blocks (y = x@W^T) interleaved with edge-scatter blocks.
// Edge thread: bucket-cursor atomic (64B-padded counters) + 8B/4B stores.
__global__ __launch_bounds__(256) void k_fused(
    const float* __restrict__ x, const float* __restrict__ Wt,
    float* __restrict__ y, const int* __restrict__ ei,
    const float* __restrict__ ew, int* __restrict__ tcur,
    int* __restrict__ scur, int2* __restrict__ tedges,
    int* __restrict__ sedges, int* __restrict__ spillcnt,
    int4* __restrict__ spillT, int2* __restrict__ spillS,
    const int* __restrict__ flag, int N, int E, int Gg, int T) {
  __shared__ float Xs[GROWS * D];
  const int B = blockIdx.x;
  const int tid = threadIdx.x;
  const long long gb = ((long long)B * Gg) / T;
  const long long gb1 = ((long long)(B + 1) * Gg) / T;

  if (gb1 > gb) {
    // ---- GEMM block ----
    const int row0 = (int)gb * GROWS;
    for (int f = tid; f < GROWS * D / 4; f += 256) {
      int r = row0 + ((f * 4) >> 7);
      float4 v = make_float4(0.f, 0.f, 0.f, 0.f);
      if (r < N)
        v = reinterpret_cast<const float4*>(x)[(size_t)row0 * (D / 4) + f];
      reinterpret_cast<float4*>(Xs)[f] = v;
    }
    __syncthreads();

    const int c0 = (tid & 31) * 4;
    const int r0 = (tid >> 5) * 4;
    float acc[4][4];
#pragma unroll
    for (int i = 0; i < 4; ++i)
#pragma unroll
      for (int j = 0; j < 4; ++j) acc[i][j] = 0.f;

#pragma unroll 4
    for (int k = 0; k < D; ++k) {
      float4 wv = reinterpret_cast<const float4*>(Wt)[(k * D + c0) >> 2];
      float xr[4];
#pragma unroll
      for (int i = 0; i < 4; ++i) xr[i] = Xs[(r0 + i) * D + k];
#pragma unroll
      for (int i = 0; i < 4; ++i) {
        acc[i][0] += xr[i] * wv.x;
        acc[i][1] += xr[i] * wv.y;
        acc[i][2] += xr[i] * wv.z;
        acc[i][3] += xr[i] * wv.w;
      }
    }
#pragma unroll
    for (int i = 0; i < 4; ++i) {
      int row = row0 + r0 + i;
      if (row < N)
        reinterpret_cast<float4*>(y)[((size_t)row * D + c0) >> 2] =
            make_float4(acc[i][0], acc[i][1], acc[i][2], acc[i][3]);
    }
  } else {
    // ---- edge-scatter block ----
    const int e = (B - (int)gb) * 256 + tid;
    if (e < E) {
      int s, t;
      if (flag[0]) {
        s = reinterpret_cast<const int2*>(ei)[e].x;
        t = reinterpret_cast<const int2*>(ei)[E + e].x;
      } else {
        s = ei[e];
        t = ei[E + e];
      }
      int wb = __float_as_int(ew[e]);
      int tb = t >> 6, sb = s >> 6;
      int rt = atomicAdd(&tcur[tb * 16], 1);  // *16: one 64B line per counter
      if (rt < TCAP) {
        tedges[(size_t)tb * TCAP + rt] = make_int2(s | ((t & 63) << 17), wb);
      } else {
        int k = atomicAdd(&spillcnt[0], 1);
        if (k < TSPILL) spillT[k] = make_int4(s, t, wb, 0);
      }
      int rs = atomicAdd(&scur[sb * 16], 1);
      if (rs < SCAP) {
        // pack slo into low 6 mantissa bits of w (4e-6 rel perturbation)
        sedges[(size_t)sb * SCAP + rs] = (wb & ~63) | (s & 63);
      } else {
        int k = atomicAdd(&spillcnt[1], 1);
        if (k < SSPILL) spillS[k] = make_int2(s, wb);
      }
    }
  }
}

// degree per src bucket: LDS histogram, coalesced write (no global atomics)
__global__ __launch_bounds__(64) void k_deg(const int* __restrict__ scur,
                                            const int* __restrict__ sedges,
                                            float* __restrict__ deg) {
  __shared__ float dsum[64];
  const int bkt = blockIdx.x, tid = threadIdx.x;
  dsum[tid] = 0.f;
  __syncthreads();
  const int cnt = min(scur[bkt * 16], SCAP);
  const int* base = sedges + (size_t)bkt * SCAP;
  for (int i = tid; i < cnt; i += 64) {
    int pk = base[i];
    atomicAdd(&dsum[pk & 63], __int_as_float(pk & ~63));
  }
  __syncthreads();
  deg[bkt * 64 + tid] = dsum[tid];  // raw sum; dinv = rsqrt(deg+1) on the fly
}

__global__ __launch_bounds__(256) void k_degspill(const int* __restrict__ spillcnt,
                                                  const int2* __restrict__ spillS,
                                                  float* __restrict__ deg) {
  int n = min(spillcnt[1], SSPILL);
  int i = blockIdx.x * 256 + threadIdx.x;
  if (i < n) atomicAdd(&deg[spillS[i].x], __int_as_float(spillS[i].y));
}

// aggregate per tgt bucket: 64x128 f32 LDS tile; wave loads 64 edge recs
// coalesced, computes wn lane-parallel, broadcasts via shfl, streams y rows
// (float2/lane) into ds_add_f32 (2-way bank aliasing = free).
__global__ __launch_bounds__(256) void k_agg(const int* __restrict__ tcur,
                                             const int2* __restrict__ tedges,
                                             const float* __restrict__ y,
                                             const float* __restrict__ deg,
                                             const float* __restrict__ b,
                                             float* __restrict__ out, int N) {
  __shared__ float tile[64 * D];  // 32 KB
  __shared__ float dtile[64];
  const int bkt = blockIdx.x;
  const int tid = threadIdx.x;
  const int wave = tid >> 6, lane = tid & 63;

  float4* t4 = reinterpret_cast<float4*>(tile);
  for (int f = tid; f < 64 * 32; f += 256) t4[f] = make_float4(0.f, 0.f, 0.f, 0.f);
  if (tid < 64) {
    int node = (bkt << 6) + tid;
    dtile[tid] = (node < N) ? rsqrtf(deg[node] + 1.0f) : 0.f;
  }
  __syncthreads();

  const int cnt = min(tcur[bkt * 16], TCAP);
  const int2* base = tedges + (size_t)bkt * TCAP;
  const float2* y2 = reinterpret_cast<const float2*>(y);
  const int nchunk = (cnt + 63) >> 6;

  for (int c = wave; c < nchunk; c += 4) {
    const int j0 = c << 6;
    const int myidx = j0 + lane;
    int recx = 0;
    float wn = 0.f;
    if (myidx < cnt) {
      int2 rec = base[myidx];  // coalesced dwordx2
      recx = rec.x;
      float ds = deg[recx & 0x1FFFF];         // gather (L2-hot 200KB table)
      float dt = dtile[recx >> 17];           // LDS gather
      wn = __int_as_float(rec.y) * rsqrtf(ds + 1.0f) * dt;
    }
    const int m = min(64, cnt - j0);
    int j = 0;
    for (; j + 4 <= m; j += 4) {
      int r0 = __shfl(recx, j), r1 = __shfl(recx, j + 1);
      int r2 = __shfl(recx, j + 2), r3 = __shfl(recx, j + 3);
      float w0 = __shfl(wn, j), w1 = __shfl(wn, j + 1);
      float w2 = __shfl(wn, j + 2), w3 = __shfl(wn, j + 3);
      float2 v0 = y2[(size_t)(r0 & 0x1FFFF) * 64 + lane];
      float2 v1 = y2[(size_t)(r1 & 0x1FFFF) * 64 + lane];
      float2 v2 = y2[(size_t)(r2 & 0x1FFFF) * 64 + lane];
      float2 v3 = y2[(size_t)(r3 & 0x1FFFF) * 64 + lane];
      atomicAdd(&tile[(r0 >> 17) * D + 2 * lane], w0 * v0.x);
      atomicAdd(&tile[(r0 >> 17) * D + 2 * lane + 1], w0 * v0.y);
      atomicAdd(&tile[(r1 >> 17) * D + 2 * lane], w1 * v1.x);
      atomicAdd(&tile[(r1 >> 17) * D + 2 * lane + 1], w1 * v1.y);
      atomicAdd(&tile[(r2 >> 17) * D + 2 * lane], w2 * v2.x);
      atomicAdd(&tile[(r2 >> 17) * D + 2 * lane + 1], w2 * v2.y);
      atomicAdd(&tile[(r3 >> 17) * D + 2 * lane], w3 * v3.x);
      atomicAdd(&tile[(r3 >> 17) * D + 2 * lane + 1], w3 * v3.y);
    }
    for (; j < m; ++j) {
      int r0 = __shfl(recx, j);
      float w0 = __shfl(wn, j);
      float2 v0 = y2[(size_t)(r0 & 0x1FFFF) * 64 + lane];
      atomicAdd(&tile[(r0 >> 17) * D + 2 * lane], w0 * v0.x);
      atomicAdd(&tile[(r0 >> 17) * D + 2 * lane + 1], w0 * v0.y);
    }
  }
  __syncthreads();

  // epilogue: out = b + tile + dt^2 * y[node]
  const float4* y4g = reinterpret_cast<const float4*>(y);
  const float4* b4 = reinterpret_cast<const float4*>(b);
  for (int f = tid; f < 64 * 32; f += 256) {
    int n = f >> 5, c4 = f & 31;
    int node = (bkt << 6) + n;
    if (node >= N) continue;
    float dt = dtile[n];
    float d2 = dt * dt;
    float4 acc = t4[f];
    float4 yv = y4g[(size_t)node * 32 + c4];
    float4 bb = b4[c4];
    float4 r;
    r.x = bb.x + acc.x + d2 * yv.x;
    r.y = bb.y + acc.y + d2 * yv.y;
    r.z = bb.z + acc.z + d2 * yv.z;
    r.w = bb.w + acc.w + d2 * yv.w;
    reinterpret_cast<float4*>(out)[(size_t)node * 32 + c4] = r;
  }
}

__global__ __launch_bounds__(128) void k_aggspill(const int* __restrict__ spillcnt,
                                                  const int4* __restrict__ spillT,
                                                  const float* __restrict__ y,
                                                  const float* __restrict__ deg,
                                                  float* __restrict__ out) {
  int n = min(spillcnt[0], TSPILL);
  int j = threadIdx.x;
  for (int e = blockIdx.x; e < n; e += gridDim.x) {
    int4 r = spillT[e];
    float wn = __int_as_float(r.z) * rsqrtf(deg[r.x] + 1.0f) *
               rsqrtf(deg[r.y] + 1.0f);
    atomicAdd(&out[(size_t)r.y * D + j], wn * y[(size_t)r.x * D + j]);
  }
}

extern "C" void kernel_launch(void* const* d_in, const int* in_sizes, int n_in,
                              void* d_out, int out_size, void* d_ws, size_t ws_size,
                              hipStream_t stream) {
  const float* x = (const float*)d_in[0];
  const int* ei = (const int*)d_in[1];
  const float* ew = (const float*)d_in[2];
  const float* W = (const float*)d_in[3];
  const float* b = (const float*)d_in[4];
  float* out = (float*)d_out;

  const int N = in_sizes[0] / D;
  const int E = in_sizes[2];
  const int NBK = (N + 63) >> 6;  // 64-node buckets

  char* ws = (char*)d_ws;
  size_t off = 0;
  auto alloc = [&](size_t bytes) {
    char* p = ws + off;
    off = (off + bytes + 255) & ~(size_t)255;
    return p;
  };
  float* deg = (float*)alloc((size_t)NBK * 64 * 4);
  float* Wt = (float*)alloc((size_t)D * D * 4);
  float* y = (float*)alloc((size_t)N * D * 4);
  int2* tedges = (int2*)alloc((size_t)NBK * TCAP * 8);
  int* sedges = (int*)alloc((size_t)NBK * SCAP * 4);
  int* tcur = (int*)alloc((size_t)NBK * 16 * 4);      // 64B-padded counters
  int* scur = (int*)alloc((size_t)NBK * 16 * 4);
  int* spillcnt = (int*)alloc(2 * 4);
  int4* spillT = (int4*)alloc((size_t)TSPILL * 16);
  int2* spillS = (int2*)alloc((size_t)SSPILL * 8);
  int* flag = (int*)alloc(4);

  // zero cursors + spill counters (contiguous region)
  hipMemsetAsync(tcur, 0, (size_t)((char*)spillT - (char*)tcur), stream);
  hipLaunchKernelGGL(k_setup, dim3((D * D + 255) / 256), dim3(256), 0, stream,
                     W, ei, Wt, flag);

  const int Gg = (N + GROWS - 1) / GROWS;
  const int Ge = (E + 255) / 256;
  const int T = Gg + Ge;
  hipLaunchKernelGGL(k_fused, dim3(T), dim3(256), 0, stream,
                     x, Wt, y, ei, ew, tcur, scur, tedges, sedges,
                     spillcnt, spillT, spillS, flag, N, E, Gg, T);
  hipLaunchKernelGGL(k_deg, dim3(NBK), dim3(64), 0, stream, scur, sedges, deg);
  hipLaunchKernelGGL(k_degspill, dim3((SSPILL + 255) / 256), dim3(256), 0,
                     stream, spillcnt, spillS, deg);
  hipLaunchKernelGGL(k_agg, dim3(NBK), dim3(256), 0, stream,
                     tcur, tedges, y, deg, b, out, N);
  hipLaunchKernelGGL(k_aggspill, dim3(64), dim3(128), 0, stream,
                     spillcnt, spillT, y, deg, out);
}

// Round 5
// 228.903 us; speedup vs baseline: 3.0853x; 3.0853x over previous
//
#include <hip/hip_runtime.h>

#define D 128
#define GROWS 32
#define RNG 13312   // nodes per histogram range (52 KB LDS per block)
#define HCHUNKS 64  // edge chunks for the degree histogram

// ---------------------------------------------------------------------------
// GCN: out = A_norm @ (x @ W^T) + b.
// R1: per-edge f32 atomics write through HBM (300MB) -> CSR gather.
// R2: 2-atomics/edge pass = 37MB atomic sectors ~ 58us wall.
// R3: fusing GEMM didn't hide it (throughput-bound, it stacked).
// R4: bucket LDS-tile agg regressed 537us (serial shfl loop, 50% L3 miss).
// R5: back to R3 CSR-gather structure; rank = 1 atomic/edge (cnt only);
// degree via privatized LDS histograms (no global atomics); y stored bf16
// (halves gather traffic); gather unrolled to 8 rows in flight.
// ---------------------------------------------------------------------------

__device__ __forceinline__ unsigned bf16rne(float f) {
  unsigned u = __float_as_uint(f);
  return (u + 0x7FFFu + ((u >> 16) & 1u)) >> 16;
}

__device__ __forceinline__ float4 bf16x4(uint2 u) {
  float4 r;
  r.x = __uint_as_float(u.x << 16);
  r.y = __uint_as_float(u.x & 0xFFFF0000u);
  r.z = __uint_as_float(u.y << 16);
  r.w = __uint_as_float(u.y & 0xFFFF0000u);
  return r;
}

__global__ __launch_bounds__(256) void k_setup(const float* __restrict__ W,
                                               const int* __restrict__ ei,
                                               float* __restrict__ Wt,
                                               int* __restrict__ flag) {
  int i = blockIdx.x * 256 + threadIdx.x;
  if (i < D * D) {
    int c = i >> 7, k = i & 127;
    Wt[k * D + c] = W[i];  // transpose for coalesced GEMM reads
  }
  if (i == 0) {
    // int64-vs-int32 edge_index layout: ids < 2^31 so int64(LE) odd dwords==0
    flag[0] = (ei[1] == 0 && ei[3] == 0 && ei[5] == 0 && ei[7] == 0) ? 1 : 0;
  }
}

// y = x @ W^T, stored as bf16 (halves gather-side traffic; ~0.004 abs err)
__global__ __launch_bounds__(256) void k_gemm(const float* __restrict__ x,
                                              const float* __restrict__ Wt,
                                              uint2* __restrict__ yb,
                                              int N) {
  __shared__ float Xs[GROWS * D];
  const int tid = threadIdx.x;
  const int row0 = blockIdx.x * GROWS;

  for (int f = tid; f < GROWS * D / 4; f += 256) {
    int r = row0 + ((f * 4) >> 7);
    float4 v = make_float4(0.f, 0.f, 0.f, 0.f);
    if (r < N)
      v = reinterpret_cast<const float4*>(x)[(size_t)row0 * (D / 4) + f];
    reinterpret_cast<float4*>(Xs)[f] = v;
  }
  __syncthreads();

  const int c0 = (tid & 31) * 4;
  const int r0 = (tid >> 5) * 4;
  float acc[4][4];
#pragma unroll
  for (int i = 0; i < 4; ++i)
#pragma unroll
    for (int j = 0; j < 4; ++j) acc[i][j] = 0.f;

#pragma unroll 4
  for (int k = 0; k < D; ++k) {
    float4 wv = reinterpret_cast<const float4*>(Wt)[(k * D + c0) >> 2];
    float xr[4];
#pragma unroll
    for (int i = 0; i < 4; ++i) xr[i] = Xs[(r0 + i) * D + k];
#pragma unroll
    for (int i = 0; i < 4; ++i) {
      acc[i][0] += xr[i] * wv.x;
      acc[i][1] += xr[i] * wv.y;
      acc[i][2] += xr[i] * wv.z;
      acc[i][3] += xr[i] * wv.w;
    }
  }
#pragma unroll
  for (int i = 0; i < 4; ++i) {
    int row = row0 + r0 + i;
    if (row < N) {
      uint2 u;
      u.x = bf16rne(acc[i][0]) | (bf16rne(acc[i][1]) << 16);
      u.y = bf16rne(acc[i][2]) | (bf16rne(acc[i][3]) << 16);
      yb[(size_t)row * 32 + (tid & 31)] = u;
    }
  }
}

// rank pass: ONE atomic per edge (19MB atomic sectors vs R2's 37MB)
__global__ __launch_bounds__(256) void k_rank(const int* __restrict__ ei,
                                              int* __restrict__ cnt,
                                              int* __restrict__ rank,
                                              const int* __restrict__ flag,
                                              int E) {
  int e = blockIdx.x * 256 + threadIdx.x;
  if (e >= E) return;
  int t = flag[0] ? reinterpret_cast<const int2*>(ei)[E + e].x : ei[E + e];
  rank[e] = atomicAdd(&cnt[t], 1);
}

// degree: privatized LDS histograms, no global atomics.
// grid (HCHUNKS, nranges): block histograms its edge chunk for its node range.
__global__ __launch_bounds__(256) void k_deghist(const int* __restrict__ ei,
                                                 const float* __restrict__ ew,
                                                 float* __restrict__ partial,
                                                 const int* __restrict__ flag,
                                                 int E) {
  __shared__ float h[RNG];
  const int tid = threadIdx.x;
  const int chunk = blockIdx.x, r = blockIdx.y;
  const int lo = r * RNG;
  for (int i = tid; i < RNG; i += 256) h[i] = 0.f;
  __syncthreads();

  const int epc = (E + HCHUNKS - 1) / HCHUNKS;
  const int e0 = chunk * epc;
  const int e1 = min(e0 + epc, E);
  const bool f64 = flag[0] != 0;
  for (int e = e0 + tid; e < e1; e += 256) {
    int s = f64 ? reinterpret_cast<const int2*>(ei)[e].x : ei[e];
    int d = s - lo;
    if ((unsigned)d < (unsigned)RNG) atomicAdd(&h[d], ew[e]);
  }
  __syncthreads();
  float* dst = partial + ((size_t)r * HCHUNKS + chunk) * RNG;
  for (int i = tid; i < RNG; i += 256) dst[i] = h[i];
}

// reduce partials across chunks; dinv = rsqrt(deg + 1)  (self-loop weight)
__global__ __launch_bounds__(256) void k_degred(const float* __restrict__ partial,
                                                float* __restrict__ dinv,
                                                int N) {
  int i = blockIdx.x * 256 + threadIdx.x;
  if (i >= N) return;
  int r = i / RNG, off = i - r * RNG;
  const float* base = partial + (size_t)r * HCHUNKS * RNG + off;
  float s = 0.f;
#pragma unroll 8
  for (int c = 0; c < HCHUNKS; ++c) s += base[(size_t)c * RNG];
  dinv[i] = rsqrtf(s + 1.0f);
}

__device__ __forceinline__ int wave_incl_scan(int v, int lane) {
#pragma unroll
  for (int o = 1; o < 64; o <<= 1) {
    int t = __shfl_up(v, o);
    if (lane >= o) v += t;
  }
  return v;
}

__global__ __launch_bounds__(256) void k_scan1(const int* __restrict__ cnt,
                                               int* __restrict__ rowptr,
                                               int* __restrict__ blocksum,
                                               int N) {
  __shared__ int wtot[4];
  int tid = threadIdx.x;
  int i = blockIdx.x * 256 + tid;
  int v = (i < N) ? cnt[i] : 0;
  int lane = tid & 63, wv = tid >> 6;
  int inc = wave_incl_scan(v, lane);
  if (lane == 63) wtot[wv] = inc;
  __syncthreads();
  if (tid == 0) {
    int r = 0;
#pragma unroll
    for (int k = 0; k < 4; ++k) { int t = wtot[k]; wtot[k] = r; r += t; }
  }
  __syncthreads();
  int exc = wtot[wv] + inc - v;
  if (i < N) rowptr[i] = exc;
  if (tid == 255) blocksum[blockIdx.x] = wtot[3] + inc;
}

__global__ __launch_bounds__(64) void k_scan2(int* __restrict__ blocksum,
                                              int* __restrict__ blockoff,
                                              int nb) {
  int lane = threadIdx.x;
  int carry = 0;
  for (int base = 0; base < nb; base += 64) {
    int idx = base + lane;
    int v = (idx < nb) ? blocksum[idx] : 0;
    int inc = wave_incl_scan(v, lane);
    if (idx < nb) blockoff[idx] = carry + inc - v;
    carry += __shfl(inc, 63);
  }
}

__global__ __launch_bounds__(256) void k_scan3(int* __restrict__ rowptr,
                                               const int* __restrict__ blockoff,
                                               int N, int E) {
  int i = blockIdx.x * 256 + threadIdx.x;
  if (i < N) rowptr[i] += blockoff[blockIdx.x];
  if (i == 0) rowptr[N] = E;
}

// atomic-free scatter: pos = rowptr[t] + rank[e]; stores {src, w*dinv[s]}
__global__ __launch_bounds__(256) void k_scatter(const int* __restrict__ ei,
                                                 const float* __restrict__ w,
                                                 const float* __restrict__ dinv,
                                                 const int* __restrict__ rowptr,
                                                 const int* __restrict__ rank,
                                                 int2* __restrict__ edges,
                                                 const int* __restrict__ flag,
                                                 int E) {
  int e = blockIdx.x * 256 + threadIdx.x;
  if (e >= E) return;
  int s, t;
  if (flag[0]) {
    s = reinterpret_cast<const int2*>(ei)[e].x;
    t = reinterpret_cast<const int2*>(ei)[E + e].x;
  } else {
    s = ei[e];
    t = ei[E + e];
  }
  float wn = w[e] * dinv[s];  // dinv[t] applied once per node in gather
  edges[rowptr[t] + rank[e]] = make_int2(s, __float_as_int(wn));
}

// gather: node per wave; 32-lane halves, 4 bf16/lane, 8 rows in flight.
// out = b + dt*(sum_e wn*y[s] + dt*y[node])
__global__ __launch_bounds__(256) void k_gather(const int* __restrict__ rowptr,
                                                const int2* __restrict__ edges,
                                                const uint2* __restrict__ yb,
                                                const float* __restrict__ dinv,
                                                const float* __restrict__ b,
                                                float* __restrict__ out,
                                                int N) {
  const int tid = threadIdx.x;
  const int node = blockIdx.x * 4 + (tid >> 6);
  if (node >= N) return;
  const int lane = tid & 63, half = lane >> 5, l32 = lane & 31;

  const float dt = dinv[node];
  const float4 yself = bf16x4(yb[(size_t)node * 32 + l32]);
  const float4 bb = reinterpret_cast<const float4*>(b)[l32];

  float4 acc = make_float4(0.f, 0.f, 0.f, 0.f);
  const int end = rowptr[node + 1];
  int e = rowptr[node] + half;
  for (; e + 6 < end; e += 8) {  // 4 rows in flight per half
    int2 e0 = edges[e], e1 = edges[e + 2], e2 = edges[e + 4], e3 = edges[e + 6];
    float4 v0 = bf16x4(yb[(size_t)e0.x * 32 + l32]);
    float4 v1 = bf16x4(yb[(size_t)e1.x * 32 + l32]);
    float4 v2 = bf16x4(yb[(size_t)e2.x * 32 + l32]);
    float4 v3 = bf16x4(yb[(size_t)e3.x * 32 + l32]);
    float w0 = __int_as_float(e0.y), w1 = __int_as_float(e1.y);
    float w2 = __int_as_float(e2.y), w3 = __int_as_float(e3.y);
    acc.x += w0 * v0.x; acc.y += w0 * v0.y; acc.z += w0 * v0.z; acc.w += w0 * v0.w;
    acc.x += w1 * v1.x; acc.y += w1 * v1.y; acc.z += w1 * v1.z; acc.w += w1 * v1.w;
    acc.x += w2 * v2.x; acc.y += w2 * v2.y; acc.z += w2 * v2.z; acc.w += w2 * v2.w;
    acc.x += w3 * v3.x; acc.y += w3 * v3.y; acc.z += w3 * v3.z; acc.w += w3 * v3.w;
  }
  for (; e < end; e += 2) {
    int2 e0 = edges[e];
    float4 v0 = bf16x4(yb[(size_t)e0.x * 32 + l32]);
    float w0 = __int_as_float(e0.y);
    acc.x += w0 * v0.x; acc.y += w0 * v0.y; acc.z += w0 * v0.z; acc.w += w0 * v0.w;
  }
  acc.x += __shfl(acc.x, l32 + 32);
  acc.y += __shfl(acc.y, l32 + 32);
  acc.z += __shfl(acc.z, l32 + 32);
  acc.w += __shfl(acc.w, l32 + 32);
  if (half == 0) {
    float4 r;
    r.x = bb.x + dt * (acc.x + dt * yself.x);
    r.y = bb.y + dt * (acc.y + dt * yself.y);
    r.z = bb.z + dt * (acc.z + dt * yself.z);
    r.w = bb.w + dt * (acc.w + dt * yself.w);
    reinterpret_cast<float4*>(out)[(size_t)node * 32 + l32] = r;
  }
}

extern "C" void kernel_launch(void* const* d_in, const int* in_sizes, int n_in,
                              void* d_out, int out_size, void* d_ws, size_t ws_size,
                              hipStream_t stream) {
  const float* x = (const float*)d_in[0];
  const int* ei = (const int*)d_in[1];
  const float* ew = (const float*)d_in[2];
  const float* W = (const float*)d_in[3];
  const float* b = (const float*)d_in[4];
  float* out = (float*)d_out;

  const int N = in_sizes[0] / D;
  const int E = in_sizes[2];
  const int NB = (N + 255) / 256;
  const int nranges = (N + RNG - 1) / RNG;

  char* ws = (char*)d_ws;
  size_t off = 0;
  auto alloc = [&](size_t bytes) {
    char* p = ws + off;
    off = (off + bytes + 255) & ~(size_t)255;
    return p;
  };
  float* Wt = (float*)alloc((size_t)D * D * 4);
  uint2* yb = (uint2*)alloc((size_t)N * D * 2);  // bf16 y
  float* dinv = (float*)alloc((size_t)N * 4);
  float* partial = (float*)alloc((size_t)nranges * HCHUNKS * RNG * 4);
  int* cnt = (int*)alloc((size_t)N * 4);
  int* rank = (int*)alloc((size_t)E * 4);
  int* rowptr = (int*)alloc((size_t)(N + 1) * 4);
  int* blocksum = (int*)alloc((size_t)NB * 4);
  int* blockoff = (int*)alloc((size_t)NB * 4);
  int2* edges = (int2*)alloc((size_t)E * 8);
  int* flag = (int*)alloc(4);

  hipMemsetAsync(cnt, 0, (size_t)N * 4, stream);
  hipLaunchKernelGGL(k_setup, dim3((D * D + 255) / 256), dim3(256), 0, stream,
                     W, ei, Wt, flag);
  hipLaunchKernelGGL(k_gemm, dim3((N + GROWS - 1) / GROWS), dim3(256), 0,
                     stream, x, Wt, yb, N);
  hipLaunchKernelGGL(k_deghist, dim3(HCHUNKS, nranges), dim3(256), 0, stream,
                     ei, ew, partial, flag, E);
  hipLaunchKernelGGL(k_degred, dim3(NB), dim3(256), 0, stream,
                     partial, dinv, N);
  hipLaunchKernelGGL(k_rank, dim3((E + 255) / 256), dim3(256), 0, stream,
                     ei, cnt, rank, flag, E);
  hipLaunchKernelGGL(k_scan1, dim3(NB), dim3(256), 0, stream,
                     cnt, rowptr, blocksum, N);
  hipLaunchKernelGGL(k_scan2, dim3(1), dim3(64), 0, stream,
                     blocksum, blockoff, NB);
  hipLaunchKernelGGL(k_scan3, dim3(NB), dim3(256), 0, stream,
                     rowptr, blockoff, N, E);
  hipLaunchKernelGGL(k_scatter, dim3((E + 255) / 256), dim3(256), 0, stream,
                     ei, ew, dinv, rowptr, rank, edges, flag, E);
  hipLaunchKernelGGL(k_gather, dim3((N + 3) / 4), dim3(256), 0, stream,
                     rowptr, edges, yb, dinv, b, out, N);
}